// Round 1
// baseline (341.560 us; speedup 1.0000x reference)
//
#include <hip/hip_runtime.h>

#define EPSV 1e-5f

constexpr int kB = 16, kC = 3, kT = 256, kV = 25;
constexpr int kMID = 48, kNB = 4, kOUT = 192, kN = 48;
constexpr int kS  = kB * kT * kV;   // 102400 sites (b,t,v)
constexpr int kTV = kT * kV;        // 6400

// ---------------- Phase A: conv1x1 + BN(global) + relu chain ----------------
// Each layer kernel: reads PREV raw pre-BN activations + prev stats, normalizes
// on the fly (scale/shift from global sums), does the channel matmul, writes raw
// output + accumulates per-channel (sum, sumsq) via wave-reduce + atomics.

template<int CIN, int COUT, bool FIRST>
__global__ __launch_bounds__(256) void mlp_small_in(
    const float* __restrict__ in, const float* __restrict__ in_stats,
    const float* __restrict__ g_prev, const float* __restrict__ be_prev,
    const float* __restrict__ w, const float* __restrict__ bias,
    float* __restrict__ out, float* __restrict__ out_stats)
{
  __shared__ float sc[CIN], sh[CIN];
  __shared__ float wl[COUT * CIN];
  __shared__ float bl[COUT];
  __shared__ float statl[2 * COUT];
  const int tid = threadIdx.x;
  for (int j = tid; j < COUT * CIN; j += 256) wl[j] = w[j];
  for (int j = tid; j < COUT; j += 256) bl[j] = bias[j];
  for (int j = tid; j < 2 * COUT; j += 256) statl[j] = 0.f;
  if constexpr (!FIRST) {
    if (tid < CIN) {
      float m  = in_stats[2 * tid] * (1.f / kS);
      float vr = in_stats[2 * tid + 1] * (1.f / kS) - m * m;
      float scale = g_prev[tid] * rsqrtf(vr + EPSV);
      sc[tid] = scale;
      sh[tid] = be_prev[tid] - m * scale;
    }
  }
  __syncthreads();
  const int s = blockIdx.x * 256 + tid;  // grid = 400 exactly covers kS
  float hv[CIN];
  if constexpr (FIRST) {
    int b = s / kTV, r = s - b * kTV;
    #pragma unroll
    for (int c = 0; c < CIN; c++) hv[c] = in[(b * kC + c) * kTV + r];
  } else {
    #pragma unroll
    for (int c = 0; c < CIN; c++)
      hv[c] = fmaxf(fmaf(in[c * kS + s], sc[c], sh[c]), 0.f);
  }
  for (int o = 0; o < COUT; o++) {
    float acc = bl[o];
    #pragma unroll
    for (int c = 0; c < CIN; c++) acc = fmaf(hv[c], wl[o * CIN + c], acc);
    out[o * kS + s] = acc;
    float s1 = acc, s2 = acc * acc;
    #pragma unroll
    for (int d = 32; d > 0; d >>= 1) { s1 += __shfl_xor(s1, d); s2 += __shfl_xor(s2, d); }
    if ((tid & 63) == 0) { atomicAdd(&statl[2 * o], s1); atomicAdd(&statl[2 * o + 1], s2); }
  }
  __syncthreads();
  for (int j = tid; j < 2 * COUT; j += 256) atomicAdd(&out_stats[j], statl[j]);
}

template<int CIN, int COUT>
__global__ __launch_bounds__(256) void mlp_big_in(
    const float* __restrict__ in, const float* __restrict__ in_stats,
    const float* __restrict__ g_prev, const float* __restrict__ be_prev,
    const float* __restrict__ w, const float* __restrict__ bias,
    float* __restrict__ out, float* __restrict__ out_stats)
{
  __shared__ float sc[CIN], sh[CIN];
  __shared__ float wl[COUT * CIN];
  __shared__ float bl[COUT];
  __shared__ float statl[2 * COUT];
  const int tid = threadIdx.x;
  for (int j = tid; j < COUT * CIN; j += 256) wl[j] = w[j];
  for (int j = tid; j < COUT; j += 256) bl[j] = bias[j];
  for (int j = tid; j < 2 * COUT; j += 256) statl[j] = 0.f;
  if (tid < CIN) {
    float m  = in_stats[2 * tid] * (1.f / kS);
    float vr = in_stats[2 * tid + 1] * (1.f / kS) - m * m;
    float scale = g_prev[tid] * rsqrtf(vr + EPSV);
    sc[tid] = scale;
    sh[tid] = be_prev[tid] - m * scale;
  }
  __syncthreads();
  const int s = blockIdx.x * 256 + tid;
  float acc[COUT];
  #pragma unroll
  for (int o = 0; o < COUT; o++) acc[o] = bl[o];
  for (int c = 0; c < CIN; c++) {
    float hc = fmaxf(fmaf(in[c * kS + s], sc[c], sh[c]), 0.f);
    #pragma unroll
    for (int o = 0; o < COUT; o++) acc[o] = fmaf(hc, wl[o * CIN + c], acc[o]);
  }
  for (int o = 0; o < COUT; o++) {
    out[o * kS + s] = acc[o];
    float s1 = acc[o], s2 = acc[o] * acc[o];
    #pragma unroll
    for (int d = 32; d > 0; d >>= 1) { s1 += __shfl_xor(s1, d); s2 += __shfl_xor(s2, d); }
    if ((tid & 63) == 0) { atomicAdd(&statl[2 * o], s1); atomicAdd(&statl[2 * o + 1], s2); }
  }
  __syncthreads();
  for (int j = tid; j < 2 * COUT; j += 256) atomicAdd(&out_stats[j], statl[j]);
}

// mean over T of relu(bn(y4)) -> hp[b][v]
__global__ void pool_kernel(const float* __restrict__ y4, const float* __restrict__ st4,
                            const float* __restrict__ g, const float* __restrict__ be,
                            float* __restrict__ hp)
{
  int tid = blockIdx.x * blockDim.x + threadIdx.x;
  if (tid >= kB * kV) return;
  float m  = st4[0] * (1.f / kS);
  float vr = st4[1] * (1.f / kS) - m * m;
  float scale = g[0] * rsqrtf(vr + EPSV);
  float shift = be[0] - m * scale;
  int b = tid / kV, v = tid - b * kV;
  float sum = 0.f;
  for (int t = 0; t < kT; t++)
    sum += fmaxf(fmaf(y4[b * kTV + t * kV + v], scale, shift), 0.f);
  hp[tid] = sum * (1.f / kT);
}

// tiny FC head: hp(16,25) -> 100 -> 192 with per-batch BN; outputs xg (b-major) + xgT (o-major)
__global__ __launch_bounds__(256) void head_kernel(
    const float* __restrict__ hp,
    const float* __restrict__ cw0, const float* __restrict__ cb0,
    const float* __restrict__ cg0, const float* __restrict__ cbe0,
    const float* __restrict__ cw1, const float* __restrict__ cb1,
    const float* __restrict__ cg1, const float* __restrict__ cbe1,
    float* __restrict__ xg, float* __restrict__ xgT)
{
  __shared__ float hpl[400];
  __shared__ float y1[100 * 16];
  __shared__ float y2l[192 * 16];
  const int tid = threadIdx.x;
  for (int j = tid; j < 400; j += 256) hpl[j] = hp[j];
  __syncthreads();
  for (int j = tid; j < 1600; j += 256) {
    int o = j >> 4, b = j & 15;
    float acc = cb0[o];
    for (int v = 0; v < 25; v++) acc = fmaf(hpl[b * 25 + v], cw0[o * 25 + v], acc);
    y1[o * 16 + b] = acc;
  }
  __syncthreads();
  if (tid < 100) {
    float s1 = 0.f, s2 = 0.f;
    for (int b = 0; b < 16; b++) { float val = y1[tid * 16 + b]; s1 += val; s2 += val * val; }
    float m = s1 * (1.f / 16), vr = s2 * (1.f / 16) - m * m;
    float scale = cg0[tid] * rsqrtf(vr + EPSV);
    float shift = cbe0[tid] - m * scale;
    for (int b = 0; b < 16; b++)
      y1[tid * 16 + b] = fmaxf(fmaf(y1[tid * 16 + b], scale, shift), 0.f);
  }
  __syncthreads();
  for (int j = tid; j < 3072; j += 256) {
    int o = j >> 4, b = j & 15;
    float acc = cb1[o];
    for (int c = 0; c < 100; c++) acc = fmaf(y1[c * 16 + b], cw1[o * 100 + c], acc);
    y2l[o * 16 + b] = acc;
  }
  __syncthreads();
  if (tid < 192) {
    float s1 = 0.f, s2 = 0.f;
    for (int b = 0; b < 16; b++) { float val = y2l[tid * 16 + b]; s1 += val; s2 += val * val; }
    float m = s1 * (1.f / 16), vr = s2 * (1.f / 16) - m * m;
    float scale = cg1[tid] * rsqrtf(vr + EPSV);
    float shift = cbe1[tid] - m * scale;
    for (int b = 0; b < 16; b++) {
      float r = fmaxf(fmaf(y2l[tid * 16 + b], scale, shift), 0.f);
      xg[b * 192 + tid]  = r;
      xgT[tid * 16 + b]  = r;
    }
  }
}

// ---------------- Phase B: fused dilated conv + gate + relu + Ww-dot + loss --------
// WG = (v, n). Per-thread register tile: 12 m x 4 t per dilation.
__global__ __launch_bounds__(256) void conv_fuse(
    const float* __restrict__ x, const float* __restrict__ Wb,
    const float* __restrict__ bb, const float* __restrict__ Ww,
    const float* __restrict__ bw, const float* __restrict__ xg,
    float* __restrict__ out_loss)
{
  __shared__ __align__(16) float xs[25 * 264];   // [ci][8 + t], 8 zeros of causal history
  __shared__ __align__(16) float wbl[75 * 48];   // [(ci*3+k)][m]  (transposed for float4 m-loads)
  __shared__ float wwl[25 * 193];                // Ww padded to stride 193 (bank-conflict-free)
  __shared__ float xgl[192];
  __shared__ float bbl[192];
  __shared__ float bwl[25];
  const int tid = threadIdx.x;
  const int wg = blockIdx.x;
  const int v = wg % 25, n = wg / 25;
  const int b = n / 3;

  for (int j = tid; j < 6400; j += 256) {        // coalesced global read, LDS scatter
    int t = j / 25, ci = j - t * 25;
    xs[ci * 264 + 8 + t] = x[n * 6400 + j];
  }
  for (int j = tid; j < 200; j += 256) {
    int ci = j >> 3, q = j & 7;
    xs[ci * 264 + q] = 0.f;
  }
  for (int j = tid; j < 4800; j += 256) {
    int vv = j / 192, o = j - vv * 192;
    wwl[vv * 193 + o] = Ww[j];
  }
  for (int j = tid; j < 192; j += 256) {
    xgl[j] = xg[b * 192 + j];
    int i = j / 48, m = j - i * 48;
    bbl[j] = bb[(i * 25 + v) * 48 + m];
  }
  if (tid < 25) bwl[tid] = bw[tid];

  const int mq = tid & 3, tl = tid >> 2;
  int wwbase[4], tp_[4], vp_[4];
  #pragma unroll
  for (int tt = 0; tt < 4; tt++) {
    int flat = v * 256 + tl + 64 * tt;           // flat = v*T + t  ->  (t', v')
    tp_[tt] = flat / 25;
    vp_[tt] = flat - tp_[tt] * 25;
    wwbase[tt] = vp_[tt] * 193;
  }
  float accout[4] = {0.f, 0.f, 0.f, 0.f};

  for (int i = 0; i < 4; i++) {
    __syncthreads();
    const float* wsrc = Wb + (i * 25 + v) * 3600;
    for (int j = tid; j < 3600; j += 256) {      // coalesced read, transposed LDS write
      int m = j / 75, q = j - m * 75;
      wbl[q * 48 + m] = wsrc[j];
    }
    __syncthreads();
    const int d = i + 1;                          // DILS = (1,2,3,4)
    float conv[12][4];
    #pragma unroll
    for (int mi = 0; mi < 12; mi++) {
      float bv = bbl[i * 48 + mq * 12 + mi];
      #pragma unroll
      for (int tt = 0; tt < 4; tt++) conv[mi][tt] = bv;
    }
    for (int ci = 0; ci < 25; ci++) {
      const float* xrow  = &xs[ci * 264 + 8 + tl];
      const float* wrow0 = &wbl[(ci * 3) * 48 + mq * 12];
      #pragma unroll
      for (int k = 0; k < 3; k++) {
        const int off = (k - 2) * d;              // taps at t-2d, t-d, t
        const float4 wa  = *(const float4*)(wrow0 + k * 48);
        const float4 wb2 = *(const float4*)(wrow0 + k * 48 + 4);
        const float4 wc  = *(const float4*)(wrow0 + k * 48 + 8);
        const float wr[12] = {wa.x, wa.y, wa.z, wa.w,
                              wb2.x, wb2.y, wb2.z, wb2.w,
                              wc.x, wc.y, wc.z, wc.w};
        float xv[4];
        #pragma unroll
        for (int tt = 0; tt < 4; tt++) xv[tt] = xrow[64 * tt + off];
        #pragma unroll
        for (int mi = 0; mi < 12; mi++)
          #pragma unroll
          for (int tt = 0; tt < 4; tt++)
            conv[mi][tt] = fmaf(xv[tt], wr[mi], conv[mi][tt]);
      }
    }
    #pragma unroll
    for (int mi = 0; mi < 12; mi++) {
      const int o = i * 48 + mq * 12 + mi;
      const float gate = xgl[o];
      #pragma unroll
      for (int tt = 0; tt < 4; tt++) {
        float z = fmaxf(gate * conv[mi][tt], 0.f);
        accout[tt] = fmaf(z, wwl[wwbase[tt] + o], accout[tt]);
      }
    }
  }
  #pragma unroll
  for (int tt = 0; tt < 4; tt++) {
    float a = accout[tt];
    a += __shfl_xor(a, 1);
    a += __shfl_xor(a, 2);
    if (mq == 0 && tp_[tt] < 255) {
      float pf = a + bwl[vp_[tt]];
      float xn = x[n * 6400 + (tp_[tt] + 1) * 25 + vp_[tt]];
      float dd = pf - xn;
      out_loss[(n * 25 + vp_[tt]) * 255 + tp_[tt]] = dd * dd;
    }
  }
}

// ---------------- Phase C: gc max + group-lasso reg ----------------
__global__ __launch_bounds__(256) void gc_reg_kernel(
    const float* __restrict__ Wb, const float* __restrict__ xgT,
    float* __restrict__ gc_out, float* __restrict__ reg_out)
{
  __shared__ float xgl[192 * 16];   // [o][b]
  __shared__ float red[256];
  const int tid = threadIdx.x;
  for (int j = tid; j < 3072; j += 256) xgl[j] = xgT[j];
  __syncthreads();
  const int site = blockIdx.x * 256 + tid;   // site = (v1*25+v2)*16 + b
  float contrib = 0.f;
  if (site < 10000) {
    const int bidx = site & 15;
    const int v1v2 = site >> 4;
    const int v1 = v1v2 / 25, v2 = v1v2 - v1 * 25;
    float s0 = 0.f, s1 = 0.f, s2 = 0.f, mx = -3.0e38f;
    for (int i = 0; i < 4; i++) {
      const float* wp = Wb + (i * 25 + v1) * 3600 + v2 * 3;
      for (int m = 0; m < 48; m++) {
        float g = xgl[(i * 48 + m) * 16 + bidx];
        const float* w3 = wp + m * 75;
        float a0 = w3[0] * g, a1 = w3[1] * g, a2 = w3[2] * g;
        s0 = fmaf(a0, a0, s0);
        s1 = fmaf(a1, a1, s1);
        s2 = fmaf(a2, a2, s2);
        mx = fmaxf(mx, fmaxf(fmaxf(a0, a1), a2));
      }
    }
    gc_out[(bidx * 25 + v1) * 25 + v2] = mx;
    contrib = sqrtf(s0 + s1 + s2) + sqrtf(s0) + sqrtf(s1) + sqrtf(s2);
  }
  red[tid] = contrib;
  __syncthreads();
  for (int st = 128; st > 0; st >>= 1) {
    if (tid < st) red[tid] += red[tid + st];
    __syncthreads();
  }
  if (tid == 0) atomicAdd(reg_out, 0.01f * red[0]);
}

extern "C" void kernel_launch(void* const* d_in, const int* in_sizes, int n_in,
                              void* d_out, int out_size, void* d_ws, size_t ws_size,
                              hipStream_t stream)
{
  const float* x    = (const float*)d_in[0];
  const float* Wb   = (const float*)d_in[1];
  const float* bb   = (const float*)d_in[2];
  const float* fw0  = (const float*)d_in[3];
  const float* fb0  = (const float*)d_in[4];
  const float* fg0  = (const float*)d_in[5];
  const float* fbe0 = (const float*)d_in[6];
  const float* fw1  = (const float*)d_in[7];
  const float* fb1  = (const float*)d_in[8];
  const float* fg1  = (const float*)d_in[9];
  const float* fbe1 = (const float*)d_in[10];
  const float* fw2  = (const float*)d_in[11];
  const float* fb2  = (const float*)d_in[12];
  const float* fg2  = (const float*)d_in[13];
  const float* fbe2 = (const float*)d_in[14];
  const float* fw3  = (const float*)d_in[15];
  const float* fb3  = (const float*)d_in[16];
  const float* fg3  = (const float*)d_in[17];
  const float* fbe3 = (const float*)d_in[18];
  const float* cw0  = (const float*)d_in[19];
  const float* cb0  = (const float*)d_in[20];
  const float* cg0  = (const float*)d_in[21];
  const float* cbe0 = (const float*)d_in[22];
  const float* cw1  = (const float*)d_in[23];
  const float* cb1  = (const float*)d_in[24];
  const float* cg1  = (const float*)d_in[25];
  const float* cbe1 = (const float*)d_in[26];
  const float* Ww   = (const float*)d_in[27];
  const float* bw   = (const float*)d_in[28];

  float* ws  = (float*)d_ws;
  float* out = (float*)d_out;

  float* Y1  = ws;                 // 10 * kS
  float* Y2  = Y1 + 10 * kS;       // 100 * kS
  float* Y3  = Y2 + 100 * kS;      // 10 * kS
  float* Y4  = Y3 + 10 * kS;       // kS
  float* ST1 = Y4 + kS;            // 20
  float* ST2 = ST1 + 20;           // 200
  float* ST3 = ST2 + 200;          // 20
  float* ST4 = ST3 + 20;           // 2
  float* HP  = ST4 + 2;            // 400
  float* XG  = HP + 400;           // 3072 (b-major)
  float* XGT = XG + 3072;          // 3072 (o-major)

  hipMemsetAsync(ST1, 0, (20 + 200 + 20 + 2) * sizeof(float), stream);
  hipMemsetAsync(out + 316000, 0, sizeof(float), stream);  // reg scalar

  mlp_small_in<3, 10, true><<<400, 256, 0, stream>>>(x, nullptr, nullptr, nullptr, fw0, fb0, Y1, ST1);
  mlp_small_in<10, 100, false><<<400, 256, 0, stream>>>(Y1, ST1, fg0, fbe0, fw1, fb1, Y2, ST2);
  mlp_big_in<100, 10><<<400, 256, 0, stream>>>(Y2, ST2, fg1, fbe1, fw2, fb2, Y3, ST3);
  mlp_small_in<10, 1, false><<<400, 256, 0, stream>>>(Y3, ST3, fg2, fbe2, fw3, fb3, Y4, ST4);
  pool_kernel<<<2, 256, 0, stream>>>(Y4, ST4, fg3, fbe3, HP);
  head_kernel<<<1, 256, 0, stream>>>(HP, cw0, cb0, cg0, cbe0, cw1, cb1, cg1, cbe1, XG, XGT);
  conv_fuse<<<1200, 256, 0, stream>>>(x, Wb, bb, Ww, bw, XG, out);
  gc_reg_kernel<<<40, 256, 0, stream>>>(Wb, XGT, out + 306000, out + 316000);
}